// Round 1
// 899.049 us; speedup vs baseline: 1.2253x; 1.2253x over previous
//
#include <hip/hip_runtime.h>

// TopKActivation: keep top-k values per row of x[B, D], zero the rest.
// One 256-thread block per row. Row elements live in registers as
// order-preserving uint32 keys. The exact k-th key is found by 4-pass
// 8-bit MSB radix select over a conflict-free LDS histogram (256 bins x
// 32 lane-columns), instead of 32-pass binary search: 4 full-key scans
// instead of 32. Ties broken by lowest index (stable top_k semantics).
// Single global read + single global write.

#define DCOLS 16384
#define TPB 256
#define CHUNKS (DCOLS / 4 / TPB) /* 16 float4 chunks per thread */
#define KPT (CHUNKS * 4)         /* 64 keys per thread */
#define NSUB 32                  /* histogram sub-columns (bank spread) */

__device__ __forceinline__ unsigned enc_f32(float f) {
    unsigned u = __float_as_uint(f);
    // positive: flip sign bit; negative: flip all bits -> monotonic uint order
    return u ^ ((unsigned)((int)u >> 31) | 0x80000000u);
}

__device__ __forceinline__ float dec_f32(unsigned kk) {
    // inverse of enc_f32 (bit-exact)
    unsigned u = kk ^ (0x80000000u | ~(unsigned)((int)kk >> 31));
    return __uint_as_float(u);
}

__global__ __launch_bounds__(TPB, 4) void topk_act_kernel(
        const float* __restrict__ x, const int* __restrict__ kptr,
        float* __restrict__ out) {
    const int tid = threadIdx.x;
    const long long row = blockIdx.x;
    const float4* __restrict__ xr = (const float4*)x + row * (DCOLS / 4);
    float4* __restrict__ outr = (float4*)out + row * (DCOLS / 4);

    // hist[bin][col]: bin = current 8-bit digit (256 real bins + 1 dump bin
    // for predicated-off lanes in passes 2..4; dump row is never read or
    // zeroed). col = lane&31 -> ds_add bank = lane&31: conflict-free.
    __shared__ __align__(16) unsigned hist[257 * NSUB]; // ~32.9 KB
    __shared__ __align__(16) unsigned bintot[256];      // 1 KB
    __shared__ int meta[4]; // {digit, new base, cntE}

    // Rare exact-tie scratch aliases hist (hist is dead by the tie pass).
    unsigned short* epfx = (unsigned short*)hist; // CHUNKS*TPB u16 = 8 KB

    uint4* h4 = (uint4*)hist; // zero the 256 real bins (2048 uint4)
#pragma unroll
    for (int j = 0; j < 8; ++j) h4[j * TPB + tid] = make_uint4(0u, 0u, 0u, 0u);

    unsigned key[KPT];
#pragma unroll
    for (int j = 0; j < CHUNKS; ++j) {
        float4 v = xr[j * TPB + tid];
        key[j * 4 + 0] = enc_f32(v.x);
        key[j * 4 + 1] = enc_f32(v.y);
        key[j * 4 + 2] = enc_f32(v.z);
        key[j * 4 + 3] = enc_f32(v.w);
    }
    const int k = *kptr;
    __syncthreads(); // hist zero visible before any ds_add

    if (k >= DCOLS || k <= 0) {
        const bool keep_all = (k >= DCOLS);
#pragma unroll
        for (int j = 0; j < CHUNKS; ++j) {
            float4 o;
            o.x = keep_all ? dec_f32(key[j * 4 + 0]) : 0.0f;
            o.y = keep_all ? dec_f32(key[j * 4 + 1]) : 0.0f;
            o.z = keep_all ? dec_f32(key[j * 4 + 2]) : 0.0f;
            o.w = keep_all ? dec_f32(key[j * 4 + 3]) : 0.0f;
            outr[j * TPB + tid] = o;
        }
        return;
    }

    const int col = tid & (NSUB - 1);

    // Pass-0 accumulate: digit = bits 31:24 of every key.
#pragma unroll
    for (int i = 0; i < KPT; ++i)
        atomicAdd(&hist[(key[i] >> 24) * NSUB + col], 1u);

    unsigned prefix = 0u; // resolved high bits of the k-th largest key
    int base = 0;         // count of keys strictly above current prefix zone
    int cntE = 0;         // keys matching full prefix after last pass

#pragma unroll
    for (int pass = 0; pass < 4; ++pass) {
        const int shift = 24 - 8 * pass;
        __syncthreads(); // this pass's ds_adds done

        // Per-bin totals: thread tid sums its bin's 32 columns with a
        // tid-staggered start so lane l hits bank (l+c)&31 each step
        // (2 lanes/bank = free).
        {
            const unsigned* hb = &hist[tid * NSUB];
            unsigned s = 0;
            int idx = tid & (NSUB - 1);
#pragma unroll
            for (int c = 0; c < NSUB; ++c) {
                s += hb[idx];
                idx = (idx + 1) & (NSUB - 1);
            }
            bintot[tid] = s;
        }
        __syncthreads(); // bintot ready

        // Wave 0: suffix-scan 256 bin totals, find digit d0 with
        // base + count(digit > d0) < k <= base + count(digit >= d0).
        if (tid < 64) {
            const uint4 t4 = ((const uint4*)bintot)[tid]; // bins 4t..4t+3
            const unsigned s = t4.x + t4.y + t4.z + t4.w;
            unsigned v = s; // inclusive suffix sum over lanes
#pragma unroll
            for (int off = 1; off < 64; off <<= 1) {
                unsigned t = __shfl_down(v, off);
                v += (tid + off < 64) ? t : 0u;
            }
            const int lsuf = (int)(v - s); // sum over lanes > tid
            const int need = k - base;     // 1 <= need
            const int g3 = lsuf;
            const int g2 = g3 + (int)t4.w;
            const int g1 = g2 + (int)t4.z;
            const int g0 = g1 + (int)t4.y;
            int d = -1, g = 0, e = 0;
            if (g3 < need && need <= g2) { d = 4 * tid + 3; g = g3; e = (int)t4.w; }
            else if (g2 < need && need <= g1) { d = 4 * tid + 2; g = g2; e = (int)t4.z; }
            else if (g1 < need && need <= g0) { d = 4 * tid + 1; g = g1; e = (int)t4.y; }
            else if (g0 < need && need <= g0 + (int)t4.x) { d = 4 * tid; g = g0; e = (int)t4.x; }
            if (d >= 0) { // exactly one lane wins
                meta[0] = d;
                meta[1] = base + g;
                meta[2] = e;
            }
        }
        // Re-zero hist for the next pass (reads of hist finished pre-barrier).
        if (pass < 3) {
#pragma unroll
            for (int j = 0; j < 8; ++j)
                h4[j * TPB + tid] = make_uint4(0u, 0u, 0u, 0u);
        }
        __syncthreads(); // meta + zeroed hist visible

        prefix |= (unsigned)meta[0] << shift;
        base = meta[1];
        cntE = meta[2];

        if (pass < 3) {
            const int nshift = shift - 8;
            const unsigned pm = prefix >> shift;
            // Branchless predication: non-matching keys go to dump bin 256.
#pragma unroll
            for (int i = 0; i < KPT; ++i) {
                const unsigned b = ((key[i] >> shift) == pm)
                                       ? ((key[i] >> nshift) & 255u)
                                       : 256u;
                atomicAdd(&hist[b * NSUB + col], 1u);
            }
        }
    }

    const unsigned ts = prefix; // k-th largest key (exact)
    const int cntG = base;      // count(key > ts)
    const int r = k - cntG;     // 1 <= r <= cntE: equals to keep

    unsigned long long keepmask = ~0ull; // common case: keep all equals
    if (r != cntE) {
        // Rare path (exact fp32 ties at the threshold): rank equals by global
        // index, keep the first r. Global index of (j, tid, c) = (j*256+tid)*4+c
        // -> lexicographic in (j, tid, c) == linear in m = j*256+tid (then c).
        unsigned long long eqmask = 0ull;
#pragma unroll
        for (int i = 0; i < KPT; ++i)
            if (key[i] == ts) eqmask |= (1ull << i);
#pragma unroll
        for (int j = 0; j < CHUNKS; ++j) {
            unsigned nib = (unsigned)((eqmask >> (j * 4)) & 0xFull);
            unsigned c4 = (nib & 1u) + ((nib >> 1) & 1u) + ((nib >> 2) & 1u) +
                          ((nib >> 3) & 1u);
            epfx[j * TPB + tid] = (unsigned short)c4;
        }
        __syncthreads();
        if (tid == 0) { // serial exclusive prefix over 4096 entries; rare path
            unsigned run = 0;
            for (int m = 0; m < CHUNKS * TPB; ++m) {
                unsigned vv = epfx[m];
                epfx[m] = (unsigned short)run;
                run += vv;
            }
        }
        __syncthreads();
        keepmask = 0ull;
#pragma unroll
        for (int j = 0; j < CHUNKS; ++j) {
            int bb = (int)epfx[j * TPB + tid];
#pragma unroll
            for (int c = 0; c < 4; ++c) {
                if ((eqmask >> (j * 4 + c)) & 1ull) {
                    if (bb < r) keepmask |= (1ull << (j * 4 + c));
                    bb += 1;
                }
            }
        }
    }

    // Epilogue: decode kept values bit-exactly, zero the rest; coalesced store.
#pragma unroll
    for (int j = 0; j < CHUNKS; ++j) {
        float4 o;
#pragma unroll
        for (int c = 0; c < 4; ++c) {
            const unsigned kk = key[j * 4 + c];
            const bool keep =
                (kk > ts) || ((kk == ts) && ((keepmask >> (j * 4 + c)) & 1ull));
            ((float*)&o)[c] = keep ? dec_f32(kk) : 0.0f;
        }
        outr[j * TPB + tid] = o;
    }
}

extern "C" void kernel_launch(void* const* d_in, const int* in_sizes, int n_in,
                              void* d_out, int out_size, void* d_ws,
                              size_t ws_size, hipStream_t stream) {
    const float* x = (const float*)d_in[0];
    const int* kp = (const int*)d_in[1];
    float* out = (float*)d_out;
    const int B = in_sizes[0] / DCOLS; // 8192 rows
    topk_act_kernel<<<B, TPB, 0, stream>>>(x, kp, out);
}